// Round 18
// baseline (502.683 us; speedup 1.0000x reference)
//
#include <hip/hip_runtime.h>

// MACE interaction: N=50000 nodes, E=800000 edges, C=64, R=8, H=64
// R18: R17 with the post-GEMM column-tile bug fixed (4 n-tiles -> d=0..63;
// R17 only computed d=0..31). Edge kernel = R15 exact (proven optimum).
// ws: agg N*256 f32 | cnt N i32 | xtb N*256 u16 | W1t 512 f32 | W2bf 4096 u16
//     | W3bf 16384 u16 | W0pb 4096 u16 | W1pb 4096 u16 | cursor N | perm E
//     | ers E int2   (~87 MB)

#define FDIM 256
#define INV_SQRT2 0.7071067811865476f
#define INV_SQRT3 0.5773502691896258f

typedef __attribute__((ext_vector_type(8))) short s16x8;
typedef __attribute__((ext_vector_type(4))) float fx4;

__device__ __forceinline__ float silu_f(float x) { return x / (1.0f + __expf(-x)); }

__device__ __forceinline__ unsigned short f2bf(float x) {  // RNE f32->bf16
    unsigned int u = __float_as_uint(x);
    u += 0x7FFFu + ((u >> 16) & 1u);
    return (unsigned short)(u >> 16);
}

__device__ __forceinline__ float bf2f(short v) {
    return __uint_as_float(((unsigned int)(unsigned short)v) << 16);
}

__device__ __forceinline__ int swz(int row) {
    return ((row & 7) ^ ((row >> 3) & 7)) << 4;
}

// ---------------- K1: hist + weight prep + PRE transform (fused) -------------
__global__ void __launch_bounds__(256) hist_pre_kernel(
    const int* __restrict__ ei, int* __restrict__ cnt, int E,
    const float* __restrict__ W1, const float* __restrict__ W2,
    const float* __restrict__ W3, float* __restrict__ W1t,
    unsigned short* __restrict__ W2bf, unsigned short* __restrict__ W3bf,
    const float* __restrict__ postW0, const float* __restrict__ postW1,
    unsigned short* __restrict__ W0pb, unsigned short* __restrict__ W1pb,
    const float* __restrict__ nf, const float* __restrict__ preW0,
    const float* __restrict__ preW1, unsigned short* __restrict__ xtb,
    int nNodes)
{
    int i = blockIdx.x * 256 + threadIdx.x;
    if (i < 512)  { int r = i >> 6, k = i & 63; W1t[k * 8 + r] = W1[i]; }
    if (i < 4096) {
        int j = i >> 6, k = i & 63;
        W2bf[i] = f2bf(W2[k * 64 + j]);
        W0pb[i] = f2bf(postW0[k * 64 + j]);   // [d][k] = postW0[k][d]
        W1pb[i] = f2bf(postW1[k * 64 + j]);
    }
    if (i < 16384) {
        int col = i >> 6, k = i & 63;
        int cb = col >> 5, r32 = col & 31, t = r32 >> 3, ci = r32 & 7;
        W3bf[i] = f2bf(W3[k * 256 + t * 64 + cb * 8 + ci]);
    }
    if (i < E) atomicAdd(&cnt[ei[i]], 1);   // fire-and-forget

    const int lane = threadIdx.x & 63;
    const int wave = threadIdx.x >> 6;
    const int waveId = blockIdx.x * 4 + wave;
    const int nWaves = gridDim.x * 4;

    __shared__ __align__(16) float rowL[4][2][256];

    float w0r[64], w1r[64];
#pragma unroll
    for (int c = 0; c < 64; ++c) {
        w0r[c] = preW0[c * 64 + lane];
        w1r[c] = preW1[c * 64 + lane];
    }

    int n = waveId;
    if (n < nNodes) {
        float4 rv = *reinterpret_cast<const float4*>(nf + (size_t)n * FDIM + lane * 4);
        *reinterpret_cast<float4*>(&rowL[wave][0][lane * 4]) = rv;
    }
    int buf = 0;
    for (; n < nNodes; n += nWaves, buf ^= 1) {
        const int nn = n + nWaves;
        const bool hasNext = (nn < nNodes);
        float4 rvn;
        if (hasNext)
            rvn = *reinterpret_cast<const float4*>(nf + (size_t)nn * FDIM + lane * 4);

        asm volatile("s_waitcnt lgkmcnt(0)" ::: "memory");
        __builtin_amdgcn_sched_barrier(0);

        const float* __restrict__ row = rowL[wave][buf];
        float a0 = 0.f, a1 = 0.f, a2 = 0.f, a3 = 0.f;
#pragma unroll
        for (int c4 = 0; c4 < 16; ++c4) {
            fx4 x0 = *reinterpret_cast<const fx4*>(&row[c4 * 4]);
            fx4 xa = *reinterpret_cast<const fx4*>(&row[64 + c4 * 12]);
            fx4 xb = *reinterpret_cast<const fx4*>(&row[64 + c4 * 12 + 4]);
            fx4 xc = *reinterpret_cast<const fx4*>(&row[64 + c4 * 12 + 8]);
            const int c = c4 * 4;
            a0 = fmaf(x0[0], w0r[c + 0], a0);
            a1 = fmaf(xa[0], w1r[c + 0], a1);
            a2 = fmaf(xa[1], w1r[c + 0], a2);
            a3 = fmaf(xa[2], w1r[c + 0], a3);
            a0 = fmaf(x0[1], w0r[c + 1], a0);
            a1 = fmaf(xa[3], w1r[c + 1], a1);
            a2 = fmaf(xb[0], w1r[c + 1], a2);
            a3 = fmaf(xb[1], w1r[c + 1], a3);
            a0 = fmaf(x0[2], w0r[c + 2], a0);
            a1 = fmaf(xb[2], w1r[c + 2], a1);
            a2 = fmaf(xb[3], w1r[c + 2], a2);
            a3 = fmaf(xc[0], w1r[c + 2], a3);
            a0 = fmaf(x0[3], w0r[c + 3], a0);
            a1 = fmaf(xc[1], w1r[c + 3], a1);
            a2 = fmaf(xc[2], w1r[c + 3], a2);
            a3 = fmaf(xc[3], w1r[c + 3], a3);
        }
        __builtin_amdgcn_sched_barrier(0);

        unsigned short* o = xtb + (size_t)n * FDIM + (lane >> 3) * 32 + (lane & 7);
        o[0]  = f2bf(a0 * 0.125f);
        o[8]  = f2bf(a1 * 0.125f);
        o[16] = f2bf(a2 * 0.125f);
        o[24] = f2bf(a3 * 0.125f);

        if (hasNext)
            *reinterpret_cast<float4*>(&rowL[wave][buf ^ 1][lane * 4]) = rvn;
        __builtin_amdgcn_sched_barrier(0);
    }
}

__global__ void __launch_bounds__(1024) scan_kernel(
    const int* __restrict__ cnt, int* __restrict__ cursor, int nBins)
{
    __shared__ int part[1024];
    const int t = threadIdx.x;
    const int per = (nBins + 1023) / 1024;
    const int lo = t * per;
    const int hi = (lo + per < nBins) ? lo + per : nBins;

    int s = 0;
    for (int i = lo; i < hi; ++i) s += cnt[i];
    part[t] = s;
    __syncthreads();

    for (int off = 1; off < 1024; off <<= 1) {
        int v = part[t];
        int add = (t >= off) ? part[t - off] : 0;
        __syncthreads();
        part[t] = v + add;
        __syncthreads();
    }

    int run = part[t] - s;
    for (int i = lo; i < hi; ++i) {
        cursor[i] = run;
        run += cnt[i];
    }
}

__global__ void __launch_bounds__(256) scatter_perm_kernel(
    const int* __restrict__ ei, int* __restrict__ cursor,
    int* __restrict__ perm, int2* __restrict__ ers, int E)
{
    int i = blockIdx.x * 256 + threadIdx.x;
    if (i < E) {
        int r = ei[i];
        int p = atomicAdd(&cursor[r], 1);
        perm[p] = i;
        ers[p] = make_int2(r, ei[E + i]);
    }
}

// ---------------- fused edge kernel (R15 exact: sorted, MFMA MLP, scatter) ----
__global__ void __launch_bounds__(256, 2) edge_kernel(
    const unsigned short* __restrict__ xtb, const float* __restrict__ sph,
    const float* __restrict__ rb, const int2* __restrict__ ers,
    const int* __restrict__ perm,
    const float* __restrict__ W1t, const unsigned short* __restrict__ W2bf,
    const unsigned short* __restrict__ W3bf, float* __restrict__ agg, int E)
{
    const int tid  = threadIdx.x;
    const int lane = tid & 63;
    const int wave = tid >> 6;
    const int eBase = blockIdx.x * 256 + wave * 64;   // sorted position base
    const int idx = eBase + lane;
    const int idxSafe = (idx < E) ? idx : (E - 1);
    const int pe = perm[idxSafe];                     // original edge id

    // 16KB/wave (first 8KB used) -> 2 blocks/CU: anti-churn throttle.
    // R9-R13 sweep: 4blk->1.9GB, 3blk->0.97GB, 2blk->0.36GB edge traffic.
    __shared__ __align__(16) char sbufAll[4][16384];
    __shared__ int recvL[4][64];
    char* const sbuf = sbufAll[wave];

    // ---------- layer 1: h1 = silu(rb @ W1), fp32 VALU ----------
    const float4 rq0 = *reinterpret_cast<const float4*>(rb + (size_t)pe * 8);
    const float4 rq1 = *reinterpret_cast<const float4*>(rb + (size_t)pe * 8 + 4);
    const float rbv[8] = {rq0.x, rq0.y, rq0.z, rq0.w, rq1.x, rq1.y, rq1.z, rq1.w};

    float h1[64];
#pragma unroll
    for (int k = 0; k < 64; ++k) {
        float acc = 0.f;
#pragma unroll
        for (int r = 0; r < 8; ++r) acc = fmaf(rbv[r], W1t[k * 8 + r], acc);
        h1[k] = silu_f(acc);
    }

#pragma unroll
    for (int q = 0; q < 8; ++q) {
        s16x8 v;
#pragma unroll
        for (int t = 0; t < 8; ++t) v[t] = (short)f2bf(h1[q * 8 + t]);
        *reinterpret_cast<s16x8*>(sbuf + lane * 128 + ((q * 16) ^ swz(lane))) = v;
    }

    const float4 shv = *reinterpret_cast<const float4*>(sph + (size_t)pe * 4);
    const float sh1a[3] = {shv.y, shv.z, shv.w};
    const int2 rs = ers[idxSafe];                     // coalesced (recv, send)
    recvL[wave][lane] = rs.x;
    const unsigned short* __restrict__ xrow = xtb + (size_t)rs.y * FDIM;

    const int l15 = lane & 15;
    const int g4  = lane >> 4;

    // ---------- h1 A-fragments ----------
    s16x8 aH[4][2];
#pragma unroll
    for (int m = 0; m < 4; ++m)
#pragma unroll
        for (int kk = 0; kk < 2; ++kk) {
            int row = m * 16 + l15;
            aH[m][kk] = *reinterpret_cast<const s16x8*>(
                sbuf + row * 128 + ((kk * 64 + g4 * 16) ^ swz(row)));
        }

    // ---------- layer 2 in two n-halves ----------
#pragma unroll
    for (int nh = 0; nh < 2; ++nh) {
        s16x8 bW2[2][2];
#pragma unroll
        for (int n2 = 0; n2 < 2; ++n2)
#pragma unroll
            for (int kk = 0; kk < 2; ++kk)
                bW2[n2][kk] = *reinterpret_cast<const s16x8*>(
                    W2bf + ((nh * 2 + n2) * 16 + l15) * 64 + kk * 32 + g4 * 8);

        fx4 acc2[4][2];
#pragma unroll
        for (int m = 0; m < 4; ++m)
#pragma unroll
            for (int n2 = 0; n2 < 2; ++n2) {
                fx4 z = {0.f, 0.f, 0.f, 0.f};
                acc2[m][n2] = z;
            }
#pragma unroll
        for (int kk = 0; kk < 2; ++kk)
#pragma unroll
            for (int m = 0; m < 4; ++m)
#pragma unroll
                for (int n2 = 0; n2 < 2; ++n2)
                    acc2[m][n2] = __builtin_amdgcn_mfma_f32_16x16x32_bf16(
                        aH[m][kk], bW2[n2][kk], acc2[m][n2], 0, 0, 0);

#pragma unroll
        for (int m = 0; m < 4; ++m)
#pragma unroll
            for (int n2 = 0; n2 < 2; ++n2)
#pragma unroll
                for (int r = 0; r < 4; ++r) {
                    int edge = m * 16 + g4 * 4 + r;
                    int j = (nh * 2 + n2) * 16 + l15;
                    *reinterpret_cast<unsigned short*>(
                        sbuf + edge * 128 + ((2 * j) ^ swz(edge))) =
                        f2bf(silu_f(acc2[m][n2][r]));
                }
    }

    // ---------- h2 A-fragments (live across all chunks) ----------
    s16x8 aH2[4][2];
#pragma unroll
    for (int m = 0; m < 4; ++m)
#pragma unroll
        for (int kk = 0; kk < 2; ++kk) {
            int row = m * 16 + l15;
            aH2[m][kk] = *reinterpret_cast<const s16x8*>(
                sbuf + row * 128 + ((kk * 64 + g4 * 16) ^ swz(row)));
        }

    // scatter constants (chunk-contiguous agg: addr = n*256 + cb*32 + jj)
    const int jj  = lane & 31;
    const int sub = lane >> 5;
    const int base = sub * 32;
    float* const aggJJ = agg + jj;

    // segment-boundary bitmask for this lane's half (same for all 8 chunks)
    unsigned segmask = 0;
    {
        int rp = recvL[wave][base];
#pragma unroll
        for (int ep = 1; ep < 32; ++ep) {
            int r = recvL[wave][base + ep];
            if (r != rp) segmask |= (1u << ep);
            rp = r;
        }
    }

    for (int cbp = 0; cbp < 4; ++cbp) {
        // xj gather: ONE 128B-aligned line per edge per chunk-pair
        s16x8 xjb2[8];
#pragma unroll
        for (int t = 0; t < 8; ++t)
            xjb2[t] = *reinterpret_cast<const s16x8*>(xrow + cbp * 64 + t * 8);

#pragma unroll
        for (int half = 0; half < 2; ++half) {
            const int cb = cbp * 2 + half;
            const s16x8* xjb = &xjb2[half * 4];

            // W3 B-fragments for this chunk
            s16x8 bW3[2][2];
#pragma unroll
            for (int n2 = 0; n2 < 2; ++n2)
#pragma unroll
                for (int kk = 0; kk < 2; ++kk)
                    bW3[n2][kk] = *reinterpret_cast<const s16x8*>(
                        W3bf + (cb * 32 + n2 * 16 + l15) * 64 + kk * 32 + g4 * 8);

            // layer 3 chunk: 16 MFMA
            fx4 accw[4][2];
#pragma unroll
            for (int m = 0; m < 4; ++m)
#pragma unroll
                for (int n2 = 0; n2 < 2; ++n2) {
                    fx4 z = {0.f, 0.f, 0.f, 0.f};
                    accw[m][n2] = z;
                }
#pragma unroll
            for (int kk = 0; kk < 2; ++kk)
#pragma unroll
                for (int m = 0; m < 4; ++m)
#pragma unroll
                    for (int n2 = 0; n2 < 2; ++n2)
                        accw[m][n2] = __builtin_amdgcn_mfma_f32_16x16x32_bf16(
                            aH2[m][kk], bW3[n2][kk], accw[m][n2], 0, 0, 0);

            // w -> LDS rows [edge][t*8+ci]
#pragma unroll
            for (int m = 0; m < 4; ++m)
#pragma unroll
                for (int n2 = 0; n2 < 2; ++n2)
#pragma unroll
                    for (int r = 0; r < 4; ++r) {
                        int edge = m * 16 + g4 * 4 + r;
                        int c32 = n2 * 16 + l15;
                        *reinterpret_cast<float*>(
                            sbuf + edge * 128 + ((c32 * 4) ^ swz(edge))) = accw[m][n2][r];
                    }

            // read own row's w: wv[t][ci]
            float wv[4][8];
#pragma unroll
            for (int t = 0; t < 4; ++t)
#pragma unroll
                for (int q = 0; q < 2; ++q) {
                    fx4 v = *reinterpret_cast<const fx4*>(
                        sbuf + lane * 128 + ((t * 32 + q * 16) ^ swz(lane)));
                    wv[t][q*4+0]=v.x; wv[t][q*4+1]=v.y; wv[t][q*4+2]=v.z; wv[t][q*4+3]=v.w;
                }

            // messages computed IN PLACE over wv
#pragma unroll
            for (int ci = 0; ci < 8; ++ci) {
                float x0v = bf2f(xjb[0][ci]);
                float x1a = bf2f(xjb[1][ci]);
                float x1b = bf2f(xjb[2][ci]);
                float x1c = bf2f(xjb[3][ci]);
                float dotv = (x1a * sh1a[0] + x1b * sh1a[1] + x1c * sh1a[2]) * INV_SQRT3;
                float m0 = (wv[0][ci] * x0v * shv.x + wv[1][ci] * dotv) * INV_SQRT2;
                float m1 = (wv[2][ci] * x0v * sh1a[0] + wv[3][ci] * x1a * shv.x) * INV_SQRT2;
                float m2 = (wv[2][ci] * x0v * sh1a[1] + wv[3][ci] * x1b * shv.x) * INV_SQRT2;
                float m3 = (wv[2][ci] * x0v * sh1a[2] + wv[3][ci] * x1c * shv.x) * INV_SQRT2;
                wv[0][ci] = m0; wv[1][ci] = m1; wv[2][ci] = m2; wv[3][ci] = m3;
            }
#pragma unroll
            for (int t = 0; t < 4; ++t)
#pragma unroll
                for (int q = 0; q < 2; ++q) {
                    fx4 v = {wv[t][q*4+0], wv[t][q*4+1], wv[t][q*4+2], wv[t][q*4+3]};
                    *reinterpret_cast<fx4*>(
                        sbuf + lane * 128 + ((t * 32 + q * 16) ^ swz(lane))) = v;
                }

            // ---- run-segmented scatter, contiguous halves, bitmask-driven ----
            {
                int rprev = recvL[wave][base];
                float acc = 0.f;
                bool first = true;
#pragma unroll
                for (int ep = 0; ep < 32; ++ep) {
                    const int eL = base + ep;
                    float v = *reinterpret_cast<const float*>(
                        sbuf + eL * 128 + ((jj * 4) ^ swz(eL)));
                    if (eBase + eL >= E) v = 0.f;
                    if (segmask & (1u << ep)) {
                        float* dst = aggJJ + (size_t)rprev * FDIM + cb * 32;
                        if (first) atomicAdd(dst, acc);
                        else       *dst = acc;        // complete interior segment
                        first = false;
                        acc = 0.f;
                        rprev = recvL[wave][eL];      // read only at boundaries
                    }
                    acc += v;
                }
                // last segment may continue into next half/wave -> atomic
                atomicAdd(aggJJ + (size_t)rprev * FDIM + cb * 32, acc);
            }
        }
    }
}

// ---------------- post transform as bf16 MFMA GEMM (4 column tiles) ----------
// y[n][d][t] = (sum_c agg[n][c][t] * W[c][d]) / 8,  W = postW0 (t=0) / postW1.
// agg chunk-contiguous layout [n*256 + cb*32 + t*8 + ci] makes the A-fragment
// k-slice contiguous: addr n*256 + (kk*4+g4)*32 + t*8. B from W0pb/W1pb [d][k].
// C layout: col d = nt*16+l15, row node = m*16+g4*4+r (m89-verified).
__global__ void __launch_bounds__(256) post_kernel(
    const float* __restrict__ agg, const unsigned short* __restrict__ W0pb,
    const unsigned short* __restrict__ W1pb, float* __restrict__ out, int nNodes)
{
    const int lane = threadIdx.x & 63;
    const int wave = threadIdx.x >> 6;
    const int waveId = blockIdx.x * 4 + wave;
    const int l15 = lane & 15;
    const int g4  = lane >> 4;

    const int nodeBase = waveId * 64;
    if (nodeBase >= nNodes) return;

    // B fragments (loaded once): 4 n-tiles, d = nt*16+l15, k = kk*32+g4*8
    s16x8 b0[4][2], b1[4][2];
#pragma unroll
    for (int nt = 0; nt < 4; ++nt)
#pragma unroll
        for (int kk = 0; kk < 2; ++kk) {
            b0[nt][kk] = *reinterpret_cast<const s16x8*>(
                W0pb + (nt * 16 + l15) * 64 + kk * 32 + g4 * 8);
            b1[nt][kk] = *reinterpret_cast<const s16x8*>(
                W1pb + (nt * 16 + l15) * 64 + kk * 32 + g4 * 8);
        }

#pragma unroll
    for (int t = 0; t < 4; ++t) {
        // A fragments for this t: af[kk][m]; row node = m*16+l15
        s16x8 af[2][4];
#pragma unroll
        for (int kk = 0; kk < 2; ++kk)
#pragma unroll
            for (int m = 0; m < 4; ++m) {
                int node = nodeBase + m * 16 + l15;
                if (node >= nNodes) node = nNodes - 1;   // dummy row (store guarded)
                const float* p = agg + (size_t)node * FDIM
                               + (kk * 4 + g4) * 32 + t * 8;
                fx4 u = *reinterpret_cast<const fx4*>(p);
                fx4 v = *reinterpret_cast<const fx4*>(p + 4);
                s16x8 a;
#pragma unroll
                for (int j = 0; j < 4; ++j) {
                    a[j]     = (short)f2bf(u[j]);
                    a[4 + j] = (short)f2bf(v[j]);
                }
                af[kk][m] = a;
            }

        const s16x8 (&bw)[4][2] = (t == 0) ? b0 : b1;   // folds at compile time

#pragma unroll
        for (int nt = 0; nt < 4; ++nt) {
            fx4 acc[4];
#pragma unroll
            for (int m = 0; m < 4; ++m) {
                fx4 z = {0.f, 0.f, 0.f, 0.f};
                acc[m] = z;
            }
#pragma unroll
            for (int kk = 0; kk < 2; ++kk)
#pragma unroll
                for (int m = 0; m < 4; ++m)
                    acc[m] = __builtin_amdgcn_mfma_f32_16x16x32_bf16(
                        af[kk][m], bw[nt][kk], acc[m], 0, 0, 0);

            // store: out[node*256 + d*4 + t], d = nt*16+l15, node = m*16+g4*4+r
#pragma unroll
            for (int m = 0; m < 4; ++m)
#pragma unroll
                for (int r = 0; r < 4; ++r) {
                    int node = nodeBase + m * 16 + g4 * 4 + r;
                    if (node < nNodes)
                        out[(size_t)node * FDIM + (nt * 16 + l15) * 4 + t] =
                            acc[m][r] * 0.125f;
                }
        }
    }
}

extern "C" void kernel_launch(void* const* d_in, const int* in_sizes, int n_in,
                              void* d_out, int out_size, void* d_ws, size_t ws_size,
                              hipStream_t stream) {
    const float* nf     = (const float*)d_in[0];
    const float* sph    = (const float*)d_in[1];
    const float* rb     = (const float*)d_in[2];
    const float* preW0  = (const float*)d_in[3];
    const float* preW1  = (const float*)d_in[4];
    const float* mlpW1  = (const float*)d_in[5];
    const float* mlpW2  = (const float*)d_in[6];
    const float* mlpW3  = (const float*)d_in[7];
    const float* postW0 = (const float*)d_in[8];
    const float* postW1 = (const float*)d_in[9];
    const int*   ei     = (const int*)d_in[10];

    const int N = in_sizes[0] / FDIM;   // 50000
    const int E = in_sizes[1] / 4;      // 800000

    float* agg = (float*)d_ws;                             // N*256 f32
    int* cnt = (int*)(agg + (size_t)N * FDIM);             // N i32 (adjacent -> one memset)
    unsigned short* xtb = (unsigned short*)(cnt + N);      // N*256 u16
    float* W1t = (float*)(xtb + (size_t)N * FDIM);         // 512 f32
    unsigned short* W2bf = (unsigned short*)(W1t + 512);   // 4096 u16
    unsigned short* W3bf = W2bf + 4096;                    // 16384 u16
    unsigned short* W0pb = W3bf + 16384;                   // 4096 u16
    unsigned short* W1pb = W0pb + 4096;                    // 4096 u16
    int* cursor = (int*)(W1pb + 4096);                     // N i32
    int* perm   = cursor + N;                              // E i32
    int2* ers   = (int2*)(perm + E);                       // E int2

    hipMemsetAsync(agg, 0, (size_t)N * FDIM * sizeof(float) + (size_t)N * sizeof(int),
                   stream);

    hist_pre_kernel<<<(E + 255) / 256, 256, 0, stream>>>(
        ei, cnt, E, mlpW1, mlpW2, mlpW3, W1t, W2bf, W3bf,
        postW0, postW1, W0pb, W1pb,
        nf, preW0, preW1, xtb, N);
    scan_kernel<<<1, 1024, 0, stream>>>(cnt, cursor, N);
    scatter_perm_kernel<<<(E + 255) / 256, 256, 0, stream>>>(ei, cursor, perm, ers, E);
    edge_kernel<<<(E + 255) / 256, 256, 0, stream>>>(
        xtb, sph, rb, ers, perm, W1t, W2bf, W3bf, agg, E);
    post_kernel<<<(N + 255) / 256, 256, 0, stream>>>(
        agg, W0pb, W1pb, (float*)d_out, N);
}

// Round 19
// 447.121 us; speedup vs baseline: 1.1243x; 1.1243x over previous
//
#include <hip/hip_runtime.h>

// MACE interaction: N=50000 nodes, E=800000 edges, C=64, R=8, H=64
// R19: R18 with post-GEMM stores fixed — loop reorder puts all 4 t-values
// (innermost out dim) in-register per (node,d), so each lane stores ONE
// float4 (fully dense lines, no write amplification). Edge = R15 exact.
// ws: agg N*256 f32 | cnt N i32 | xtb N*256 u16 | W1t 512 f32 | W2bf 4096 u16
//     | W3bf 16384 u16 | W0pb 4096 u16 | W1pb 4096 u16 | cursor N | perm E
//     | ers E int2   (~87 MB)

#define FDIM 256
#define INV_SQRT2 0.7071067811865476f
#define INV_SQRT3 0.5773502691896258f

typedef __attribute__((ext_vector_type(8))) short s16x8;
typedef __attribute__((ext_vector_type(4))) float fx4;

__device__ __forceinline__ float silu_f(float x) { return x / (1.0f + __expf(-x)); }

__device__ __forceinline__ unsigned short f2bf(float x) {  // RNE f32->bf16
    unsigned int u = __float_as_uint(x);
    u += 0x7FFFu + ((u >> 16) & 1u);
    return (unsigned short)(u >> 16);
}

__device__ __forceinline__ float bf2f(short v) {
    return __uint_as_float(((unsigned int)(unsigned short)v) << 16);
}

__device__ __forceinline__ int swz(int row) {
    return ((row & 7) ^ ((row >> 3) & 7)) << 4;
}

// ---------------- K1: hist + weight prep + PRE transform (fused) -------------
__global__ void __launch_bounds__(256) hist_pre_kernel(
    const int* __restrict__ ei, int* __restrict__ cnt, int E,
    const float* __restrict__ W1, const float* __restrict__ W2,
    const float* __restrict__ W3, float* __restrict__ W1t,
    unsigned short* __restrict__ W2bf, unsigned short* __restrict__ W3bf,
    const float* __restrict__ postW0, const float* __restrict__ postW1,
    unsigned short* __restrict__ W0pb, unsigned short* __restrict__ W1pb,
    const float* __restrict__ nf, const float* __restrict__ preW0,
    const float* __restrict__ preW1, unsigned short* __restrict__ xtb,
    int nNodes)
{
    int i = blockIdx.x * 256 + threadIdx.x;
    if (i < 512)  { int r = i >> 6, k = i & 63; W1t[k * 8 + r] = W1[i]; }
    if (i < 4096) {
        int j = i >> 6, k = i & 63;
        W2bf[i] = f2bf(W2[k * 64 + j]);
        W0pb[i] = f2bf(postW0[k * 64 + j]);   // [d][k] = postW0[k][d]
        W1pb[i] = f2bf(postW1[k * 64 + j]);
    }
    if (i < 16384) {
        int col = i >> 6, k = i & 63;
        int cb = col >> 5, r32 = col & 31, t = r32 >> 3, ci = r32 & 7;
        W3bf[i] = f2bf(W3[k * 256 + t * 64 + cb * 8 + ci]);
    }
    if (i < E) atomicAdd(&cnt[ei[i]], 1);   // fire-and-forget

    const int lane = threadIdx.x & 63;
    const int wave = threadIdx.x >> 6;
    const int waveId = blockIdx.x * 4 + wave;
    const int nWaves = gridDim.x * 4;

    __shared__ __align__(16) float rowL[4][2][256];

    float w0r[64], w1r[64];
#pragma unroll
    for (int c = 0; c < 64; ++c) {
        w0r[c] = preW0[c * 64 + lane];
        w1r[c] = preW1[c * 64 + lane];
    }

    int n = waveId;
    if (n < nNodes) {
        float4 rv = *reinterpret_cast<const float4*>(nf + (size_t)n * FDIM + lane * 4);
        *reinterpret_cast<float4*>(&rowL[wave][0][lane * 4]) = rv;
    }
    int buf = 0;
    for (; n < nNodes; n += nWaves, buf ^= 1) {
        const int nn = n + nWaves;
        const bool hasNext = (nn < nNodes);
        float4 rvn;
        if (hasNext)
            rvn = *reinterpret_cast<const float4*>(nf + (size_t)nn * FDIM + lane * 4);

        asm volatile("s_waitcnt lgkmcnt(0)" ::: "memory");
        __builtin_amdgcn_sched_barrier(0);

        const float* __restrict__ row = rowL[wave][buf];
        float a0 = 0.f, a1 = 0.f, a2 = 0.f, a3 = 0.f;
#pragma unroll
        for (int c4 = 0; c4 < 16; ++c4) {
            fx4 x0 = *reinterpret_cast<const fx4*>(&row[c4 * 4]);
            fx4 xa = *reinterpret_cast<const fx4*>(&row[64 + c4 * 12]);
            fx4 xb = *reinterpret_cast<const fx4*>(&row[64 + c4 * 12 + 4]);
            fx4 xc = *reinterpret_cast<const fx4*>(&row[64 + c4 * 12 + 8]);
            const int c = c4 * 4;
            a0 = fmaf(x0[0], w0r[c + 0], a0);
            a1 = fmaf(xa[0], w1r[c + 0], a1);
            a2 = fmaf(xa[1], w1r[c + 0], a2);
            a3 = fmaf(xa[2], w1r[c + 0], a3);
            a0 = fmaf(x0[1], w0r[c + 1], a0);
            a1 = fmaf(xa[3], w1r[c + 1], a1);
            a2 = fmaf(xb[0], w1r[c + 1], a2);
            a3 = fmaf(xb[1], w1r[c + 1], a3);
            a0 = fmaf(x0[2], w0r[c + 2], a0);
            a1 = fmaf(xb[2], w1r[c + 2], a1);
            a2 = fmaf(xb[3], w1r[c + 2], a2);
            a3 = fmaf(xc[0], w1r[c + 2], a3);
            a0 = fmaf(x0[3], w0r[c + 3], a0);
            a1 = fmaf(xc[1], w1r[c + 3], a1);
            a2 = fmaf(xc[2], w1r[c + 3], a2);
            a3 = fmaf(xc[3], w1r[c + 3], a3);
        }
        __builtin_amdgcn_sched_barrier(0);

        unsigned short* o = xtb + (size_t)n * FDIM + (lane >> 3) * 32 + (lane & 7);
        o[0]  = f2bf(a0 * 0.125f);
        o[8]  = f2bf(a1 * 0.125f);
        o[16] = f2bf(a2 * 0.125f);
        o[24] = f2bf(a3 * 0.125f);

        if (hasNext)
            *reinterpret_cast<float4*>(&rowL[wave][buf ^ 1][lane * 4]) = rvn;
        __builtin_amdgcn_sched_barrier(0);
    }
}

__global__ void __launch_bounds__(1024) scan_kernel(
    const int* __restrict__ cnt, int* __restrict__ cursor, int nBins)
{
    __shared__ int part[1024];
    const int t = threadIdx.x;
    const int per = (nBins + 1023) / 1024;
    const int lo = t * per;
    const int hi = (lo + per < nBins) ? lo + per : nBins;

    int s = 0;
    for (int i = lo; i < hi; ++i) s += cnt[i];
    part[t] = s;
    __syncthreads();

    for (int off = 1; off < 1024; off <<= 1) {
        int v = part[t];
        int add = (t >= off) ? part[t - off] : 0;
        __syncthreads();
        part[t] = v + add;
        __syncthreads();
    }

    int run = part[t] - s;
    for (int i = lo; i < hi; ++i) {
        cursor[i] = run;
        run += cnt[i];
    }
}

__global__ void __launch_bounds__(256) scatter_perm_kernel(
    const int* __restrict__ ei, int* __restrict__ cursor,
    int* __restrict__ perm, int2* __restrict__ ers, int E)
{
    int i = blockIdx.x * 256 + threadIdx.x;
    if (i < E) {
        int r = ei[i];
        int p = atomicAdd(&cursor[r], 1);
        perm[p] = i;
        ers[p] = make_int2(r, ei[E + i]);
    }
}

// ---------------- fused edge kernel (R15 exact: sorted, MFMA MLP, scatter) ----
__global__ void __launch_bounds__(256, 2) edge_kernel(
    const unsigned short* __restrict__ xtb, const float* __restrict__ sph,
    const float* __restrict__ rb, const int2* __restrict__ ers,
    const int* __restrict__ perm,
    const float* __restrict__ W1t, const unsigned short* __restrict__ W2bf,
    const unsigned short* __restrict__ W3bf, float* __restrict__ agg, int E)
{
    const int tid  = threadIdx.x;
    const int lane = tid & 63;
    const int wave = tid >> 6;
    const int eBase = blockIdx.x * 256 + wave * 64;   // sorted position base
    const int idx = eBase + lane;
    const int idxSafe = (idx < E) ? idx : (E - 1);
    const int pe = perm[idxSafe];                     // original edge id

    // 16KB/wave (first 8KB used) -> 2 blocks/CU: anti-churn throttle.
    // R9-R13 sweep: 4blk->1.9GB, 3blk->0.97GB, 2blk->0.36GB edge traffic.
    __shared__ __align__(16) char sbufAll[4][16384];
    __shared__ int recvL[4][64];
    char* const sbuf = sbufAll[wave];

    // ---------- layer 1: h1 = silu(rb @ W1), fp32 VALU ----------
    const float4 rq0 = *reinterpret_cast<const float4*>(rb + (size_t)pe * 8);
    const float4 rq1 = *reinterpret_cast<const float4*>(rb + (size_t)pe * 8 + 4);
    const float rbv[8] = {rq0.x, rq0.y, rq0.z, rq0.w, rq1.x, rq1.y, rq1.z, rq1.w};

    float h1[64];
#pragma unroll
    for (int k = 0; k < 64; ++k) {
        float acc = 0.f;
#pragma unroll
        for (int r = 0; r < 8; ++r) acc = fmaf(rbv[r], W1t[k * 8 + r], acc);
        h1[k] = silu_f(acc);
    }

#pragma unroll
    for (int q = 0; q < 8; ++q) {
        s16x8 v;
#pragma unroll
        for (int t = 0; t < 8; ++t) v[t] = (short)f2bf(h1[q * 8 + t]);
        *reinterpret_cast<s16x8*>(sbuf + lane * 128 + ((q * 16) ^ swz(lane))) = v;
    }

    const float4 shv = *reinterpret_cast<const float4*>(sph + (size_t)pe * 4);
    const float sh1a[3] = {shv.y, shv.z, shv.w};
    const int2 rs = ers[idxSafe];                     // coalesced (recv, send)
    recvL[wave][lane] = rs.x;
    const unsigned short* __restrict__ xrow = xtb + (size_t)rs.y * FDIM;

    const int l15 = lane & 15;
    const int g4  = lane >> 4;

    // ---------- h1 A-fragments ----------
    s16x8 aH[4][2];
#pragma unroll
    for (int m = 0; m < 4; ++m)
#pragma unroll
        for (int kk = 0; kk < 2; ++kk) {
            int row = m * 16 + l15;
            aH[m][kk] = *reinterpret_cast<const s16x8*>(
                sbuf + row * 128 + ((kk * 64 + g4 * 16) ^ swz(row)));
        }

    // ---------- layer 2 in two n-halves ----------
#pragma unroll
    for (int nh = 0; nh < 2; ++nh) {
        s16x8 bW2[2][2];
#pragma unroll
        for (int n2 = 0; n2 < 2; ++n2)
#pragma unroll
            for (int kk = 0; kk < 2; ++kk)
                bW2[n2][kk] = *reinterpret_cast<const s16x8*>(
                    W2bf + ((nh * 2 + n2) * 16 + l15) * 64 + kk * 32 + g4 * 8);

        fx4 acc2[4][2];
#pragma unroll
        for (int m = 0; m < 4; ++m)
#pragma unroll
            for (int n2 = 0; n2 < 2; ++n2) {
                fx4 z = {0.f, 0.f, 0.f, 0.f};
                acc2[m][n2] = z;
            }
#pragma unroll
        for (int kk = 0; kk < 2; ++kk)
#pragma unroll
            for (int m = 0; m < 4; ++m)
#pragma unroll
                for (int n2 = 0; n2 < 2; ++n2)
                    acc2[m][n2] = __builtin_amdgcn_mfma_f32_16x16x32_bf16(
                        aH[m][kk], bW2[n2][kk], acc2[m][n2], 0, 0, 0);

#pragma unroll
        for (int m = 0; m < 4; ++m)
#pragma unroll
            for (int n2 = 0; n2 < 2; ++n2)
#pragma unroll
                for (int r = 0; r < 4; ++r) {
                    int edge = m * 16 + g4 * 4 + r;
                    int j = (nh * 2 + n2) * 16 + l15;
                    *reinterpret_cast<unsigned short*>(
                        sbuf + edge * 128 + ((2 * j) ^ swz(edge))) =
                        f2bf(silu_f(acc2[m][n2][r]));
                }
    }

    // ---------- h2 A-fragments (live across all chunks) ----------
    s16x8 aH2[4][2];
#pragma unroll
    for (int m = 0; m < 4; ++m)
#pragma unroll
        for (int kk = 0; kk < 2; ++kk) {
            int row = m * 16 + l15;
            aH2[m][kk] = *reinterpret_cast<const s16x8*>(
                sbuf + row * 128 + ((kk * 64 + g4 * 16) ^ swz(row)));
        }

    // scatter constants (chunk-contiguous agg: addr = n*256 + cb*32 + jj)
    const int jj  = lane & 31;
    const int sub = lane >> 5;
    const int base = sub * 32;
    float* const aggJJ = agg + jj;

    // segment-boundary bitmask for this lane's half (same for all 8 chunks)
    unsigned segmask = 0;
    {
        int rp = recvL[wave][base];
#pragma unroll
        for (int ep = 1; ep < 32; ++ep) {
            int r = recvL[wave][base + ep];
            if (r != rp) segmask |= (1u << ep);
            rp = r;
        }
    }

    for (int cbp = 0; cbp < 4; ++cbp) {
        // xj gather: ONE 128B-aligned line per edge per chunk-pair
        s16x8 xjb2[8];
#pragma unroll
        for (int t = 0; t < 8; ++t)
            xjb2[t] = *reinterpret_cast<const s16x8*>(xrow + cbp * 64 + t * 8);

#pragma unroll
        for (int half = 0; half < 2; ++half) {
            const int cb = cbp * 2 + half;
            const s16x8* xjb = &xjb2[half * 4];

            // W3 B-fragments for this chunk
            s16x8 bW3[2][2];
#pragma unroll
            for (int n2 = 0; n2 < 2; ++n2)
#pragma unroll
                for (int kk = 0; kk < 2; ++kk)
                    bW3[n2][kk] = *reinterpret_cast<const s16x8*>(
                        W3bf + (cb * 32 + n2 * 16 + l15) * 64 + kk * 32 + g4 * 8);

            // layer 3 chunk: 16 MFMA
            fx4 accw[4][2];
#pragma unroll
            for (int m = 0; m < 4; ++m)
#pragma unroll
                for (int n2 = 0; n2 < 2; ++n2) {
                    fx4 z = {0.f, 0.f, 0.f, 0.f};
                    accw[m][n2] = z;
                }
#pragma unroll
            for (int kk = 0; kk < 2; ++kk)
#pragma unroll
                for (int m = 0; m < 4; ++m)
#pragma unroll
                    for (int n2 = 0; n2 < 2; ++n2)
                        accw[m][n2] = __builtin_amdgcn_mfma_f32_16x16x32_bf16(
                            aH2[m][kk], bW3[n2][kk], accw[m][n2], 0, 0, 0);

            // w -> LDS rows [edge][t*8+ci]
#pragma unroll
            for (int m = 0; m < 4; ++m)
#pragma unroll
                for (int n2 = 0; n2 < 2; ++n2)
#pragma unroll
                    for (int r = 0; r < 4; ++r) {
                        int edge = m * 16 + g4 * 4 + r;
                        int c32 = n2 * 16 + l15;
                        *reinterpret_cast<float*>(
                            sbuf + edge * 128 + ((c32 * 4) ^ swz(edge))) = accw[m][n2][r];
                    }

            // read own row's w: wv[t][ci]
            float wv[4][8];
#pragma unroll
            for (int t = 0; t < 4; ++t)
#pragma unroll
                for (int q = 0; q < 2; ++q) {
                    fx4 v = *reinterpret_cast<const fx4*>(
                        sbuf + lane * 128 + ((t * 32 + q * 16) ^ swz(lane)));
                    wv[t][q*4+0]=v.x; wv[t][q*4+1]=v.y; wv[t][q*4+2]=v.z; wv[t][q*4+3]=v.w;
                }

            // messages computed IN PLACE over wv
#pragma unroll
            for (int ci = 0; ci < 8; ++ci) {
                float x0v = bf2f(xjb[0][ci]);
                float x1a = bf2f(xjb[1][ci]);
                float x1b = bf2f(xjb[2][ci]);
                float x1c = bf2f(xjb[3][ci]);
                float dotv = (x1a * sh1a[0] + x1b * sh1a[1] + x1c * sh1a[2]) * INV_SQRT3;
                float m0 = (wv[0][ci] * x0v * shv.x + wv[1][ci] * dotv) * INV_SQRT2;
                float m1 = (wv[2][ci] * x0v * sh1a[0] + wv[3][ci] * x1a * shv.x) * INV_SQRT2;
                float m2 = (wv[2][ci] * x0v * sh1a[1] + wv[3][ci] * x1b * shv.x) * INV_SQRT2;
                float m3 = (wv[2][ci] * x0v * sh1a[2] + wv[3][ci] * x1c * shv.x) * INV_SQRT2;
                wv[0][ci] = m0; wv[1][ci] = m1; wv[2][ci] = m2; wv[3][ci] = m3;
            }
#pragma unroll
            for (int t = 0; t < 4; ++t)
#pragma unroll
                for (int q = 0; q < 2; ++q) {
                    fx4 v = {wv[t][q*4+0], wv[t][q*4+1], wv[t][q*4+2], wv[t][q*4+3]};
                    *reinterpret_cast<fx4*>(
                        sbuf + lane * 128 + ((t * 32 + q * 16) ^ swz(lane))) = v;
                }

            // ---- run-segmented scatter, contiguous halves, bitmask-driven ----
            {
                int rprev = recvL[wave][base];
                float acc = 0.f;
                bool first = true;
#pragma unroll
                for (int ep = 0; ep < 32; ++ep) {
                    const int eL = base + ep;
                    float v = *reinterpret_cast<const float*>(
                        sbuf + eL * 128 + ((jj * 4) ^ swz(eL)));
                    if (eBase + eL >= E) v = 0.f;
                    if (segmask & (1u << ep)) {
                        float* dst = aggJJ + (size_t)rprev * FDIM + cb * 32;
                        if (first) atomicAdd(dst, acc);
                        else       *dst = acc;        // complete interior segment
                        first = false;
                        acc = 0.f;
                        rprev = recvL[wave][eL];      // read only at boundaries
                    }
                    acc += v;
                }
                // last segment may continue into next half/wave -> atomic
                atomicAdd(aggJJ + (size_t)rprev * FDIM + cb * 32, acc);
            }
        }
    }
}

// ---------------- post transform as bf16 MFMA GEMM, float4 stores ------------
// y[n][d][t] = (sum_c agg[n][c][t] * W[c][d]) / 8,  W = postW0 (t=0) / postW1.
// Loop order: (m, nt) outer, all 4 t accumulated in-register BEFORE the store,
// so each lane writes ONE float4 at out[node*256 + d*4] (t innermost) —
// 16 l15-lanes cover 256B contiguous -> full lines, no write amplification.
// A-frag k-slice contiguous in agg chunk layout: addr n*256+(kk*4+g4)*32+t*8.
// C layout (m89): col d = nt*16+l15, row node = m*16+g4*4+r.
__global__ void __launch_bounds__(256) post_kernel(
    const float* __restrict__ agg, const unsigned short* __restrict__ W0pb,
    const unsigned short* __restrict__ W1pb, float* __restrict__ out, int nNodes)
{
    const int lane = threadIdx.x & 63;
    const int wave = threadIdx.x >> 6;
    const int waveId = blockIdx.x * 4 + wave;
    const int l15 = lane & 15;
    const int g4  = lane >> 4;

    const int nodeBase = waveId * 64;
    if (nodeBase >= nNodes) return;

    // B fragments (loaded once): 4 n-tiles, d = nt*16+l15, k = kk*32+g4*8
    s16x8 b0[4][2], b1[4][2];
#pragma unroll
    for (int nt = 0; nt < 4; ++nt)
#pragma unroll
        for (int kk = 0; kk < 2; ++kk) {
            b0[nt][kk] = *reinterpret_cast<const s16x8*>(
                W0pb + (nt * 16 + l15) * 64 + kk * 32 + g4 * 8);
            b1[nt][kk] = *reinterpret_cast<const s16x8*>(
                W1pb + (nt * 16 + l15) * 64 + kk * 32 + g4 * 8);
        }

#pragma unroll
    for (int m = 0; m < 4; ++m) {
        // A fragments for this node tile: af[t][kk], row node = m*16+l15
        int nodeA = nodeBase + m * 16 + l15;
        if (nodeA >= nNodes) nodeA = nNodes - 1;   // dummy row (store guarded)
        s16x8 af[4][2];
#pragma unroll
        for (int t = 0; t < 4; ++t)
#pragma unroll
            for (int kk = 0; kk < 2; ++kk) {
                const float* p = agg + (size_t)nodeA * FDIM
                               + (kk * 4 + g4) * 32 + t * 8;
                fx4 u = *reinterpret_cast<const fx4*>(p);
                fx4 v = *reinterpret_cast<const fx4*>(p + 4);
                s16x8 a;
#pragma unroll
                for (int j = 0; j < 4; ++j) {
                    a[j]     = (short)f2bf(u[j]);
                    a[4 + j] = (short)f2bf(v[j]);
                }
                af[t][kk] = a;
            }

#pragma unroll
        for (int nt = 0; nt < 4; ++nt) {
            fx4 acc[4];
#pragma unroll
            for (int t = 0; t < 4; ++t) {
                fx4 z = {0.f, 0.f, 0.f, 0.f};
                acc[t] = z;
            }
#pragma unroll
            for (int kk = 0; kk < 2; ++kk) {
                acc[0] = __builtin_amdgcn_mfma_f32_16x16x32_bf16(
                    af[0][kk], b0[nt][kk], acc[0], 0, 0, 0);
#pragma unroll
                for (int t = 1; t < 4; ++t)
                    acc[t] = __builtin_amdgcn_mfma_f32_16x16x32_bf16(
                        af[t][kk], b1[nt][kk], acc[t], 0, 0, 0);
            }

            // store: one float4 per (lane, r) at out[node*256 + d*4],
            // d = nt*16+l15, node = m*16+g4*4+r  (t=0..3 packed in the float4)
#pragma unroll
            for (int r = 0; r < 4; ++r) {
                int node = nodeBase + m * 16 + g4 * 4 + r;
                if (node < nNodes) {
                    fx4 o = {acc[0][r] * 0.125f, acc[1][r] * 0.125f,
                             acc[2][r] * 0.125f, acc[3][r] * 0.125f};
                    *reinterpret_cast<fx4*>(
                        out + (size_t)node * FDIM + (nt * 16 + l15) * 4) = o;
                }
            }
        }
    }
}

extern "C" void kernel_launch(void* const* d_in, const int* in_sizes, int n_in,
                              void* d_out, int out_size, void* d_ws, size_t ws_size,
                              hipStream_t stream) {
    const float* nf     = (const float*)d_in[0];
    const float* sph    = (const float*)d_in[1];
    const float* rb     = (const float*)d_in[2];
    const float* preW0  = (const float*)d_in[3];
    const float* preW1  = (const float*)d_in[4];
    const float* mlpW1  = (const float*)d_in[5];
    const float* mlpW2  = (const float*)d_in[6];
    const float* mlpW3  = (const float*)d_in[7];
    const float* postW0 = (const float*)d_in[8];
    const float* postW1 = (const float*)d_in[9];
    const int*   ei     = (const int*)d_in[10];

    const int N = in_sizes[0] / FDIM;   // 50000
    const int E = in_sizes[1] / 4;      // 800000

    float* agg = (float*)d_ws;                             // N*256 f32
    int* cnt = (int*)(agg + (size_t)N * FDIM);             // N i32 (adjacent -> one memset)
    unsigned short* xtb = (unsigned short*)(cnt + N);      // N*256 u16
    float* W1t = (float*)(xtb + (size_t)N * FDIM);         // 512 f32
    unsigned short* W2bf = (unsigned short*)(W1t + 512);   // 4096 u16
    unsigned short* W3bf = W2bf + 4096;                    // 16384 u16
    unsigned short* W0pb = W3bf + 16384;                   // 4096 u16
    unsigned short* W1pb = W0pb + 4096;                    // 4096 u16
    int* cursor = (int*)(W1pb + 4096);                     // N i32
    int* perm   = cursor + N;                              // E i32
    int2* ers   = (int2*)(perm + E);                       // E int2

    hipMemsetAsync(agg, 0, (size_t)N * FDIM * sizeof(float) + (size_t)N * sizeof(int),
                   stream);

    hist_pre_kernel<<<(E + 255) / 256, 256, 0, stream>>>(
        ei, cnt, E, mlpW1, mlpW2, mlpW3, W1t, W2bf, W3bf,
        postW0, postW1, W0pb, W1pb,
        nf, preW0, preW1, xtb, N);
    scan_kernel<<<1, 1024, 0, stream>>>(cnt, cursor, N);
    scatter_perm_kernel<<<(E + 255) / 256, 256, 0, stream>>>(ei, cursor, perm, ers, E);
    edge_kernel<<<(E + 255) / 256, 256, 0, stream>>>(
        xtb, sph, rb, ers, perm, W1t, W2bf, W3bf, agg, E);
    post_kernel<<<(N + 255) / 256, 256, 0, stream>>>(
        agg, W0pb, W1pb, (float*)d_out, N);
}

// Round 20
// 444.952 us; speedup vs baseline: 1.1297x; 1.0049x over previous
//
#include <hip/hip_runtime.h>

// MACE interaction: N=50000 nodes, E=800000 edges, C=64, R=8, H=64
// R20: rb/sph pre-permuted into sorted order (bf16) by scatter_perm — edge's
// random rb/sph/perm reads become coalesced streams; the randomness moves to
// write-combined scattered writes in scatter_perm. Edge else = R15 exact.
// ws: agg N*256 f32 | cnt N i32 | xtb N*256 u16 | W1t 512 f32 | W2bf 4096 u16
//     | W3bf 16384 u16 | W0pb 4096 u16 | W1pb 4096 u16 | cursor N i32
//     | ers E int2 | rbs E*8 u16 | sphs E*4 u16   (~103 MB, within proven)

#define FDIM 256
#define INV_SQRT2 0.7071067811865476f
#define INV_SQRT3 0.5773502691896258f

typedef __attribute__((ext_vector_type(8))) short s16x8;
typedef __attribute__((ext_vector_type(4))) float fx4;
typedef __attribute__((ext_vector_type(4))) unsigned short u16x4;

__device__ __forceinline__ float silu_f(float x) { return x / (1.0f + __expf(-x)); }

__device__ __forceinline__ unsigned short f2bf(float x) {  // RNE f32->bf16
    unsigned int u = __float_as_uint(x);
    u += 0x7FFFu + ((u >> 16) & 1u);
    return (unsigned short)(u >> 16);
}

__device__ __forceinline__ float bf2f(short v) {
    return __uint_as_float(((unsigned int)(unsigned short)v) << 16);
}

__device__ __forceinline__ float bf2fu(unsigned short v) {
    return __uint_as_float(((unsigned int)v) << 16);
}

__device__ __forceinline__ int swz(int row) {
    return ((row & 7) ^ ((row >> 3) & 7)) << 4;
}

// ---------------- K1: hist + weight prep + PRE transform (fused) -------------
__global__ void __launch_bounds__(256) hist_pre_kernel(
    const int* __restrict__ ei, int* __restrict__ cnt, int E,
    const float* __restrict__ W1, const float* __restrict__ W2,
    const float* __restrict__ W3, float* __restrict__ W1t,
    unsigned short* __restrict__ W2bf, unsigned short* __restrict__ W3bf,
    const float* __restrict__ postW0, const float* __restrict__ postW1,
    unsigned short* __restrict__ W0pb, unsigned short* __restrict__ W1pb,
    const float* __restrict__ nf, const float* __restrict__ preW0,
    const float* __restrict__ preW1, unsigned short* __restrict__ xtb,
    int nNodes)
{
    int i = blockIdx.x * 256 + threadIdx.x;
    if (i < 512)  { int r = i >> 6, k = i & 63; W1t[k * 8 + r] = W1[i]; }
    if (i < 4096) {
        int j = i >> 6, k = i & 63;
        W2bf[i] = f2bf(W2[k * 64 + j]);
        W0pb[i] = f2bf(postW0[k * 64 + j]);   // [d][k] = postW0[k][d]
        W1pb[i] = f2bf(postW1[k * 64 + j]);
    }
    if (i < 16384) {
        int col = i >> 6, k = i & 63;
        int cb = col >> 5, r32 = col & 31, t = r32 >> 3, ci = r32 & 7;
        W3bf[i] = f2bf(W3[k * 256 + t * 64 + cb * 8 + ci]);
    }
    if (i < E) atomicAdd(&cnt[ei[i]], 1);   // fire-and-forget

    const int lane = threadIdx.x & 63;
    const int wave = threadIdx.x >> 6;
    const int waveId = blockIdx.x * 4 + wave;
    const int nWaves = gridDim.x * 4;

    __shared__ __align__(16) float rowL[4][2][256];

    float w0r[64], w1r[64];
#pragma unroll
    for (int c = 0; c < 64; ++c) {
        w0r[c] = preW0[c * 64 + lane];
        w1r[c] = preW1[c * 64 + lane];
    }

    int n = waveId;
    if (n < nNodes) {
        float4 rv = *reinterpret_cast<const float4*>(nf + (size_t)n * FDIM + lane * 4);
        *reinterpret_cast<float4*>(&rowL[wave][0][lane * 4]) = rv;
    }
    int buf = 0;
    for (; n < nNodes; n += nWaves, buf ^= 1) {
        const int nn = n + nWaves;
        const bool hasNext = (nn < nNodes);
        float4 rvn;
        if (hasNext)
            rvn = *reinterpret_cast<const float4*>(nf + (size_t)nn * FDIM + lane * 4);

        asm volatile("s_waitcnt lgkmcnt(0)" ::: "memory");
        __builtin_amdgcn_sched_barrier(0);

        const float* __restrict__ row = rowL[wave][buf];
        float a0 = 0.f, a1 = 0.f, a2 = 0.f, a3 = 0.f;
#pragma unroll
        for (int c4 = 0; c4 < 16; ++c4) {
            fx4 x0 = *reinterpret_cast<const fx4*>(&row[c4 * 4]);
            fx4 xa = *reinterpret_cast<const fx4*>(&row[64 + c4 * 12]);
            fx4 xb = *reinterpret_cast<const fx4*>(&row[64 + c4 * 12 + 4]);
            fx4 xc = *reinterpret_cast<const fx4*>(&row[64 + c4 * 12 + 8]);
            const int c = c4 * 4;
            a0 = fmaf(x0[0], w0r[c + 0], a0);
            a1 = fmaf(xa[0], w1r[c + 0], a1);
            a2 = fmaf(xa[1], w1r[c + 0], a2);
            a3 = fmaf(xa[2], w1r[c + 0], a3);
            a0 = fmaf(x0[1], w0r[c + 1], a0);
            a1 = fmaf(xa[3], w1r[c + 1], a1);
            a2 = fmaf(xb[0], w1r[c + 1], a2);
            a3 = fmaf(xb[1], w1r[c + 1], a3);
            a0 = fmaf(x0[2], w0r[c + 2], a0);
            a1 = fmaf(xb[2], w1r[c + 2], a1);
            a2 = fmaf(xb[3], w1r[c + 2], a2);
            a3 = fmaf(xc[0], w1r[c + 2], a3);
            a0 = fmaf(x0[3], w0r[c + 3], a0);
            a1 = fmaf(xc[1], w1r[c + 3], a1);
            a2 = fmaf(xc[2], w1r[c + 3], a2);
            a3 = fmaf(xc[3], w1r[c + 3], a3);
        }
        __builtin_amdgcn_sched_barrier(0);

        unsigned short* o = xtb + (size_t)n * FDIM + (lane >> 3) * 32 + (lane & 7);
        o[0]  = f2bf(a0 * 0.125f);
        o[8]  = f2bf(a1 * 0.125f);
        o[16] = f2bf(a2 * 0.125f);
        o[24] = f2bf(a3 * 0.125f);

        if (hasNext)
            *reinterpret_cast<float4*>(&rowL[wave][buf ^ 1][lane * 4]) = rvn;
        __builtin_amdgcn_sched_barrier(0);
    }
}

__global__ void __launch_bounds__(1024) scan_kernel(
    const int* __restrict__ cnt, int* __restrict__ cursor, int nBins)
{
    __shared__ int part[1024];
    const int t = threadIdx.x;
    const int per = (nBins + 1023) / 1024;
    const int lo = t * per;
    const int hi = (lo + per < nBins) ? lo + per : nBins;

    int s = 0;
    for (int i = lo; i < hi; ++i) s += cnt[i];
    part[t] = s;
    __syncthreads();

    for (int off = 1; off < 1024; off <<= 1) {
        int v = part[t];
        int add = (t >= off) ? part[t - off] : 0;
        __syncthreads();
        part[t] = v + add;
        __syncthreads();
    }

    int run = part[t] - s;
    for (int i = lo; i < hi; ++i) {
        cursor[i] = run;
        run += cnt[i];
    }
}

// sorts edge payloads into recv-order: (recv,send) pairs + bf16 rb + bf16 sph.
// Reads are coalesced; the counting-sort randomness lands on write-combined
// scattered stores (each line fully covered exactly once across the kernel).
__global__ void __launch_bounds__(256) scatter_perm_kernel(
    const int* __restrict__ ei, int* __restrict__ cursor,
    const float* __restrict__ rb, const float* __restrict__ sph,
    int2* __restrict__ ers, unsigned short* __restrict__ rbs,
    unsigned short* __restrict__ sphs, int E)
{
    int i = blockIdx.x * 256 + threadIdx.x;
    if (i < E) {
        int r = ei[i];
        int p = atomicAdd(&cursor[r], 1);
        ers[p] = make_int2(r, ei[E + i]);

        const float4 q0 = *reinterpret_cast<const float4*>(rb + (size_t)i * 8);
        const float4 q1 = *reinterpret_cast<const float4*>(rb + (size_t)i * 8 + 4);
        s16x8 rv;
        rv[0] = (short)f2bf(q0.x); rv[1] = (short)f2bf(q0.y);
        rv[2] = (short)f2bf(q0.z); rv[3] = (short)f2bf(q0.w);
        rv[4] = (short)f2bf(q1.x); rv[5] = (short)f2bf(q1.y);
        rv[6] = (short)f2bf(q1.z); rv[7] = (short)f2bf(q1.w);
        *reinterpret_cast<s16x8*>(rbs + (size_t)p * 8) = rv;

        const float4 s4 = *reinterpret_cast<const float4*>(sph + (size_t)i * 4);
        u16x4 sv;
        sv[0] = f2bf(s4.x); sv[1] = f2bf(s4.y);
        sv[2] = f2bf(s4.z); sv[3] = f2bf(s4.w);
        *reinterpret_cast<u16x4*>(sphs + (size_t)p * 4) = sv;
    }
}

// ---------------- fused edge kernel (sorted; ALL per-edge reads coalesced) ----
__global__ void __launch_bounds__(256, 2) edge_kernel(
    const unsigned short* __restrict__ xtb, const unsigned short* __restrict__ sphs,
    const unsigned short* __restrict__ rbs, const int2* __restrict__ ers,
    const float* __restrict__ W1t, const unsigned short* __restrict__ W2bf,
    const unsigned short* __restrict__ W3bf, float* __restrict__ agg, int E)
{
    const int tid  = threadIdx.x;
    const int lane = tid & 63;
    const int wave = tid >> 6;
    const int eBase = blockIdx.x * 256 + wave * 64;   // sorted position base
    const int idx = eBase + lane;
    const int idxSafe = (idx < E) ? idx : (E - 1);

    // 16KB/wave (first 8KB used) -> 2 blocks/CU: anti-churn throttle.
    // R9-R13 sweep: 4blk->1.9GB, 3blk->0.97GB, 2blk->0.36GB edge traffic.
    __shared__ __align__(16) char sbufAll[4][16384];
    __shared__ int recvL[4][64];
    char* const sbuf = sbufAll[wave];

    // ---------- layer 1: h1 = silu(rb @ W1), fp32 VALU (bf16 rb inputs) ------
    const s16x8 rq = *reinterpret_cast<const s16x8*>(rbs + (size_t)idxSafe * 8);
    float rbv[8];
#pragma unroll
    for (int r = 0; r < 8; ++r) rbv[r] = bf2f(rq[r]);

    float h1[64];
#pragma unroll
    for (int k = 0; k < 64; ++k) {
        float acc = 0.f;
#pragma unroll
        for (int r = 0; r < 8; ++r) acc = fmaf(rbv[r], W1t[k * 8 + r], acc);
        h1[k] = silu_f(acc);
    }

#pragma unroll
    for (int q = 0; q < 8; ++q) {
        s16x8 v;
#pragma unroll
        for (int t = 0; t < 8; ++t) v[t] = (short)f2bf(h1[q * 8 + t]);
        *reinterpret_cast<s16x8*>(sbuf + lane * 128 + ((q * 16) ^ swz(lane))) = v;
    }

    const u16x4 sq = *reinterpret_cast<const u16x4*>(sphs + (size_t)idxSafe * 4);
    const float sh0v = bf2fu(sq[0]);
    const float sh1a[3] = {bf2fu(sq[1]), bf2fu(sq[2]), bf2fu(sq[3])};
    const int2 rs = ers[idxSafe];                     // coalesced (recv, send)
    recvL[wave][lane] = rs.x;
    const unsigned short* __restrict__ xrow = xtb + (size_t)rs.y * FDIM;

    const int l15 = lane & 15;
    const int g4  = lane >> 4;

    // ---------- h1 A-fragments ----------
    s16x8 aH[4][2];
#pragma unroll
    for (int m = 0; m < 4; ++m)
#pragma unroll
        for (int kk = 0; kk < 2; ++kk) {
            int row = m * 16 + l15;
            aH[m][kk] = *reinterpret_cast<const s16x8*>(
                sbuf + row * 128 + ((kk * 64 + g4 * 16) ^ swz(row)));
        }

    // ---------- layer 2 in two n-halves ----------
#pragma unroll
    for (int nh = 0; nh < 2; ++nh) {
        s16x8 bW2[2][2];
#pragma unroll
        for (int n2 = 0; n2 < 2; ++n2)
#pragma unroll
            for (int kk = 0; kk < 2; ++kk)
                bW2[n2][kk] = *reinterpret_cast<const s16x8*>(
                    W2bf + ((nh * 2 + n2) * 16 + l15) * 64 + kk * 32 + g4 * 8);

        fx4 acc2[4][2];
#pragma unroll
        for (int m = 0; m < 4; ++m)
#pragma unroll
            for (int n2 = 0; n2 < 2; ++n2) {
                fx4 z = {0.f, 0.f, 0.f, 0.f};
                acc2[m][n2] = z;
            }
#pragma unroll
        for (int kk = 0; kk < 2; ++kk)
#pragma unroll
            for (int m = 0; m < 4; ++m)
#pragma unroll
                for (int n2 = 0; n2 < 2; ++n2)
                    acc2[m][n2] = __builtin_amdgcn_mfma_f32_16x16x32_bf16(
                        aH[m][kk], bW2[n2][kk], acc2[m][n2], 0, 0, 0);

#pragma unroll
        for (int m = 0; m < 4; ++m)
#pragma unroll
            for (int n2 = 0; n2 < 2; ++n2)
#pragma unroll
                for (int r = 0; r < 4; ++r) {
                    int edge = m * 16 + g4 * 4 + r;
                    int j = (nh * 2 + n2) * 16 + l15;
                    *reinterpret_cast<unsigned short*>(
                        sbuf + edge * 128 + ((2 * j) ^ swz(edge))) =
                        f2bf(silu_f(acc2[m][n2][r]));
                }
    }

    // ---------- h2 A-fragments (live across all chunks) ----------
    s16x8 aH2[4][2];
#pragma unroll
    for (int m = 0; m < 4; ++m)
#pragma unroll
        for (int kk = 0; kk < 2; ++kk) {
            int row = m * 16 + l15;
            aH2[m][kk] = *reinterpret_cast<const s16x8*>(
                sbuf + row * 128 + ((kk * 64 + g4 * 16) ^ swz(row)));
        }

    // scatter constants (chunk-contiguous agg: addr = n*256 + cb*32 + jj)
    const int jj  = lane & 31;
    const int sub = lane >> 5;
    const int base = sub * 32;
    float* const aggJJ = agg + jj;

    // segment-boundary bitmask for this lane's half (same for all 8 chunks)
    unsigned segmask = 0;
    {
        int rp = recvL[wave][base];
#pragma unroll
        for (int ep = 1; ep < 32; ++ep) {
            int r = recvL[wave][base + ep];
            if (r != rp) segmask |= (1u << ep);
            rp = r;
        }
    }

    for (int cbp = 0; cbp < 4; ++cbp) {
        // xj gather: ONE 128B-aligned line per edge per chunk-pair
        s16x8 xjb2[8];
#pragma unroll
        for (int t = 0; t < 8; ++t)
            xjb2[t] = *reinterpret_cast<const s16x8*>(xrow + cbp * 64 + t * 8);

#pragma unroll
        for (int half = 0; half < 2; ++half) {
            const int cb = cbp * 2 + half;
            const s16x8* xjb = &xjb2[half * 4];

            // W3 B-fragments for this chunk
            s16x8 bW3[2][2];
#pragma unroll
            for (int n2 = 0; n2 < 2; ++n2)
#pragma unroll
                for (int kk = 0; kk < 2; ++kk)
                    bW3[n2][kk] = *reinterpret_cast<const s16x8*>(
                        W3bf + (cb * 32 + n2 * 16 + l15) * 64 + kk * 32 + g4 * 8);

            // layer 3 chunk: 16 MFMA
            fx4 accw[4][2];
#pragma unroll
            for (int m = 0; m < 4; ++m)
#pragma unroll
                for (int n2 = 0; n2 < 2; ++n2) {
                    fx4 z = {0.f, 0.f, 0.f, 0.f};
                    accw[m][n2] = z;
                }
#pragma unroll
            for (int kk = 0; kk < 2; ++kk)
#pragma unroll
                for (int m = 0; m < 4; ++m)
#pragma unroll
                    for (int n2 = 0; n2 < 2; ++n2)
                        accw[m][n2] = __builtin_amdgcn_mfma_f32_16x16x32_bf16(
                            aH2[m][kk], bW3[n2][kk], accw[m][n2], 0, 0, 0);

            // w -> LDS rows [edge][t*8+ci]
#pragma unroll
            for (int m = 0; m < 4; ++m)
#pragma unroll
                for (int n2 = 0; n2 < 2; ++n2)
#pragma unroll
                    for (int r = 0; r < 4; ++r) {
                        int edge = m * 16 + g4 * 4 + r;
                        int c32 = n2 * 16 + l15;
                        *reinterpret_cast<float*>(
                            sbuf + edge * 128 + ((c32 * 4) ^ swz(edge))) = accw[m][n2][r];
                    }

            // read own row's w: wv[t][ci]
            float wv[4][8];
#pragma unroll
            for (int t = 0; t < 4; ++t)
#pragma unroll
                for (int q = 0; q < 2; ++q) {
                    fx4 v = *reinterpret_cast<const fx4*>(
                        sbuf + lane * 128 + ((t * 32 + q * 16) ^ swz(lane)));
                    wv[t][q*4+0]=v.x; wv[t][q*4+1]=v.y; wv[t][q*4+2]=v.z; wv[t][q*4+3]=v.w;
                }

            // messages computed IN PLACE over wv
#pragma unroll
            for (int ci = 0; ci < 8; ++ci) {
                float x0v = bf2f(xjb[0][ci]);
                float x1a = bf2f(xjb[1][ci]);
                float x1b = bf2f(xjb[2][ci]);
                float x1c = bf2f(xjb[3][ci]);
                float dotv = (x1a * sh1a[0] + x1b * sh1a[1] + x1c * sh1a[2]) * INV_SQRT3;
                float m0 = (wv[0][ci] * x0v * sh0v + wv[1][ci] * dotv) * INV_SQRT2;
                float m1 = (wv[2][ci] * x0v * sh1a[0] + wv[3][ci] * x1a * sh0v) * INV_SQRT2;
                float m2 = (wv[2][ci] * x0v * sh1a[1] + wv[3][ci] * x1b * sh0v) * INV_SQRT2;
                float m3 = (wv[2][ci] * x0v * sh1a[2] + wv[3][ci] * x1c * sh0v) * INV_SQRT2;
                wv[0][ci] = m0; wv[1][ci] = m1; wv[2][ci] = m2; wv[3][ci] = m3;
            }
#pragma unroll
            for (int t = 0; t < 4; ++t)
#pragma unroll
                for (int q = 0; q < 2; ++q) {
                    fx4 v = {wv[t][q*4+0], wv[t][q*4+1], wv[t][q*4+2], wv[t][q*4+3]};
                    *reinterpret_cast<fx4*>(
                        sbuf + lane * 128 + ((t * 32 + q * 16) ^ swz(lane))) = v;
                }

            // ---- run-segmented scatter, contiguous halves, bitmask-driven ----
            {
                int rprev = recvL[wave][base];
                float acc = 0.f;
                bool first = true;
#pragma unroll
                for (int ep = 0; ep < 32; ++ep) {
                    const int eL = base + ep;
                    float v = *reinterpret_cast<const float*>(
                        sbuf + eL * 128 + ((jj * 4) ^ swz(eL)));
                    if (eBase + eL >= E) v = 0.f;
                    if (segmask & (1u << ep)) {
                        float* dst = aggJJ + (size_t)rprev * FDIM + cb * 32;
                        if (first) atomicAdd(dst, acc);
                        else       *dst = acc;        // complete interior segment
                        first = false;
                        acc = 0.f;
                        rprev = recvL[wave][eL];      // read only at boundaries
                    }
                    acc += v;
                }
                // last segment may continue into next half/wave -> atomic
                atomicAdd(aggJJ + (size_t)rprev * FDIM + cb * 32, acc);
            }
        }
    }
}

// ---------------- post transform as bf16 MFMA GEMM, float4 stores ------------
__global__ void __launch_bounds__(256) post_kernel(
    const float* __restrict__ agg, const unsigned short* __restrict__ W0pb,
    const unsigned short* __restrict__ W1pb, float* __restrict__ out, int nNodes)
{
    const int lane = threadIdx.x & 63;
    const int wave = threadIdx.x >> 6;
    const int waveId = blockIdx.x * 4 + wave;
    const int l15 = lane & 15;
    const int g4  = lane >> 4;

    const int nodeBase = waveId * 64;
    if (nodeBase >= nNodes) return;

    s16x8 b0[4][2], b1[4][2];
#pragma unroll
    for (int nt = 0; nt < 4; ++nt)
#pragma unroll
        for (int kk = 0; kk < 2; ++kk) {
            b0[nt][kk] = *reinterpret_cast<const s16x8*>(
                W0pb + (nt * 16 + l15) * 64 + kk * 32 + g4 * 8);
            b1[nt][kk] = *reinterpret_cast<const s16x8*>(
                W1pb + (nt * 16 + l15) * 64 + kk * 32 + g4 * 8);
        }

#pragma unroll
    for (int m = 0; m < 4; ++m) {
        int nodeA = nodeBase + m * 16 + l15;
        if (nodeA >= nNodes) nodeA = nNodes - 1;   // dummy row (store guarded)
        s16x8 af[4][2];
#pragma unroll
        for (int t = 0; t < 4; ++t)
#pragma unroll
            for (int kk = 0; kk < 2; ++kk) {
                const float* p = agg + (size_t)nodeA * FDIM
                               + (kk * 4 + g4) * 32 + t * 8;
                fx4 u = *reinterpret_cast<const fx4*>(p);
                fx4 v = *reinterpret_cast<const fx4*>(p + 4);
                s16x8 a;
#pragma unroll
                for (int j = 0; j < 4; ++j) {
                    a[j]     = (short)f2bf(u[j]);
                    a[4 + j] = (short)f2bf(v[j]);
                }
                af[t][kk] = a;
            }

#pragma unroll
        for (int nt = 0; nt < 4; ++nt) {
            fx4 acc[4];
#pragma unroll
            for (int t = 0; t < 4; ++t) {
                fx4 z = {0.f, 0.f, 0.f, 0.f};
                acc[t] = z;
            }
#pragma unroll
            for (int kk = 0; kk < 2; ++kk) {
                acc[0] = __builtin_amdgcn_mfma_f32_16x16x32_bf16(
                    af[0][kk], b0[nt][kk], acc[0], 0, 0, 0);
#pragma unroll
                for (int t = 1; t < 4; ++t)
                    acc[t] = __builtin_amdgcn_mfma_f32_16x16x32_bf16(
                        af[t][kk], b1[nt][kk], acc[t], 0, 0, 0);
            }

#pragma unroll
            for (int r = 0; r < 4; ++r) {
                int node = nodeBase + m * 16 + g4 * 4 + r;
                if (node < nNodes) {
                    fx4 o = {acc[0][r] * 0.125f, acc[1][r] * 0.125f,
                             acc[2][r] * 0.125f, acc[3][r] * 0.125f};
                    *reinterpret_cast<fx4*>(
                        out + (size_t)node * FDIM + (nt * 16 + l15) * 4) = o;
                }
            }
        }
    }
}

extern "C" void kernel_launch(void* const* d_in, const int* in_sizes, int n_in,
                              void* d_out, int out_size, void* d_ws, size_t ws_size,
                              hipStream_t stream) {
    const float* nf     = (const float*)d_in[0];
    const float* sph    = (const float*)d_in[1];
    const float* rb     = (const float*)d_in[2];
    const float* preW0  = (const float*)d_in[3];
    const float* preW1  = (const float*)d_in[4];
    const float* mlpW1  = (const float*)d_in[5];
    const float* mlpW2  = (const float*)d_in[6];
    const float* mlpW3  = (const float*)d_in[7];
    const float* postW0 = (const float*)d_in[8];
    const float* postW1 = (const float*)d_in[9];
    const int*   ei     = (const int*)d_in[10];

    const int N = in_sizes[0] / FDIM;   // 50000
    const int E = in_sizes[1] / 4;      // 800000

    float* agg = (float*)d_ws;                             // N*256 f32
    int* cnt = (int*)(agg + (size_t)N * FDIM);             // N i32 (adjacent -> one memset)
    unsigned short* xtb = (unsigned short*)(cnt + N);      // N*256 u16
    float* W1t = (float*)(xtb + (size_t)N * FDIM);         // 512 f32
    unsigned short* W2bf = (unsigned short*)(W1t + 512);   // 4096 u16
    unsigned short* W3bf = W2bf + 4096;                    // 16384 u16
    unsigned short* W0pb = W3bf + 16384;                   // 4096 u16
    unsigned short* W1pb = W0pb + 4096;                    // 4096 u16
    int* cursor = (int*)(W1pb + 4096);                     // N i32
    int2* ers   = (int2*)(cursor + N);                     // E int2
    unsigned short* rbs  = (unsigned short*)(ers + E);     // E*8 u16
    unsigned short* sphs = rbs + (size_t)E * 8;            // E*4 u16

    hipMemsetAsync(agg, 0, (size_t)N * FDIM * sizeof(float) + (size_t)N * sizeof(int),
                   stream);

    hist_pre_kernel<<<(E + 255) / 256, 256, 0, stream>>>(
        ei, cnt, E, mlpW1, mlpW2, mlpW3, W1t, W2bf, W3bf,
        postW0, postW1, W0pb, W1pb,
        nf, preW0, preW1, xtb, N);
    scan_kernel<<<1, 1024, 0, stream>>>(cnt, cursor, N);
    scatter_perm_kernel<<<(E + 255) / 256, 256, 0, stream>>>(
        ei, cursor, rb, sph, ers, rbs, sphs, E);
    edge_kernel<<<(E + 255) / 256, 256, 0, stream>>>(
        xtb, sphs, rbs, ers, W1t, W2bf, W3bf, agg, E);
    post_kernel<<<(N + 255) / 256, 256, 0, stream>>>(
        agg, W0pb, W1pb, (float*)d_out, N);
}